// Round 6
// baseline (672.956 us; speedup 1.0000x reference)
//
#include <hip/hip_runtime.h>
#include <math.h>

#define NPTS  65536
#define KNN   10
#define PK    25
#define NCOUT 64
#define GRIDB 10          // pooling grid (cell 0.1) — must match reference
#define NSEG  1000
#define GRIDC 20          // kNN search grid (cell 0.05)
#define NCELL 8000
#define CELLK 0.05f
#define R0SQ  0.002025f   // 0.045^2 collect radius: E[in-ball]=25
#define SLAB_CAP 832      // 9 cols x ~9 z-cells: mean ~663
#define LIST_CAP 48
#define LIST_STRIDE 49    // u32, odd stride -> conflict-free
#define UNRES_CAP 16384
#define INVSIG (1.0f / (2.1f * 0.05f))

// ---- workspace layout (bytes) ----
#define OFF_SORTED  0           // float4 sorted[65536]
#define OFF_HIST    1048576     // int hist[8000]
#define OFF_CSTART  1080576     // int cstart[8001]
#define OFF_CURSOR  1112580     // int cursor[8000]
#define OFF_POOL    1144592     // float: counts[1000] | spt[3000] | sinf[25000]
#define OFF_UCNT    1260592     // int unresolved count
#define OFF_ULST    1260596     // int unresolved qidx list [UNRES_CAP]
#define MEMSET_SIZE (1260596 - 1048576)   // hist..ucnt inclusive

__device__ __forceinline__ int cell_of(float px, float py, float pz) {
    int gx = min((int)(px * (float)GRIDC), GRIDC - 1);
    int gy = min((int)(py * (float)GRIDC), GRIDC - 1);
    int gz = min((int)(pz * (float)GRIDC), GRIDC - 1);
    return (gx * GRIDC + gy) * GRIDC + gz;
}

__global__ __launch_bounds__(256) void hist_kernel(
    const float* __restrict__ pts, int* __restrict__ hist)
{
    int g = blockIdx.x * 256 + threadIdx.x;
    float px = pts[g*3+0], py = pts[g*3+1], pz = pts[g*3+2];
    atomicAdd(&hist[cell_of(px, py, pz)], 1);
}

__global__ __launch_bounds__(256) void scan_kernel(
    const int* __restrict__ hist, int* __restrict__ cstart, int* __restrict__ cursor)
{
    __shared__ int part[256];
    const int t = threadIdx.x;
    const int base = t * 32;                       // 256*32 = 8192 >= 8000
    int s = 0;
    for (int i = 0; i < 32; ++i) {
        int c = base + i;
        s += (c < NCELL) ? hist[c] : 0;
    }
    part[t] = s;
    __syncthreads();
    for (int off = 1; off < 256; off <<= 1) {
        int v = (t >= off) ? part[t - off] : 0;
        __syncthreads();
        part[t] += v;
        __syncthreads();
    }
    int run = (t == 0) ? 0 : part[t - 1];
    for (int i = 0; i < 32; ++i) {
        int c = base + i;
        if (c < NCELL) {
            cstart[c] = run;
            cursor[c] = run;
            run += hist[c];
        }
    }
    if (t == 255) cstart[NCELL] = run;
}

__global__ __launch_bounds__(256) void scatter_kernel(
    const float* __restrict__ pts, int* __restrict__ cursor, float4* __restrict__ sorted)
{
    int g = blockIdx.x * 256 + threadIdx.x;
    float px = pts[g*3+0], py = pts[g*3+1], pz = pts[g*3+2];
    int c = cell_of(px, py, pz);
    int pos = atomicAdd(&cursor[c], 1);
    sorted[pos] = make_float4(px, py, pz, 0.f);
}

// branchless sorted-insert of packed u32 (d_bits | idx): 3 ops per slot
__device__ __forceinline__ void ins10(unsigned (&kd)[KNN], unsigned v) {
#pragma unroll
    for (int u = 0; u < KNN; ++u) {
        unsigned lo = min(kd[u], v);
        unsigned hi = max(kd[u], v);
        kd[u] = lo; v = hi;
    }
}

__device__ __forceinline__ void ins10_64(unsigned long long (&kd)[KNN],
                                         unsigned long long v) {
#pragma unroll
    for (int u = 0; u < KNN; ++u) {
        bool lt = v < kd[u];
        unsigned long long lo = lt ? v : kd[u];
        unsigned long long hi = lt ? kd[u] : v;
        kd[u] = lo; v = hi;
    }
}

// ---- Phase A: one wave per z-column segment; lane = query; uniform scan ----
__global__ __launch_bounds__(64) void phaseA(
    const float4* __restrict__ sorted,
    const int*    __restrict__ cstart,
    const float*  __restrict__ kern,
    float*        __restrict__ pool,
    int*          __restrict__ ucnt,
    int*          __restrict__ ulst)
{
    __shared__ float4 cand[SLAB_CAP];                // 13312 B
    __shared__ unsigned lst[64 * LIST_STRIDE];       // 12544 B
    __shared__ float kx[PK], ky[PK], kz[PK];         // 300 B
    __shared__ float lpool[4][29];                   // 464 B

    const int tid = threadIdx.x;
    const int col = blockIdx.x / 3;
    const int seg = blockIdx.x % 3;
    const int cx = col / GRIDC, cy = col % GRIDC;
    const int cz0 = (seg < 2) ? seg * 7 : 14;
    const int len = (seg < 2) ? 7 : 6;
    const int colBase = col * GRIDC;

    const int qb = cstart[colBase + cz0];
    const int qe = cstart[colBase + cz0 + len];
    const int qn = qe - qb;
    if (qn == 0) return;

    if (tid < PK) { kx[tid]=kern[tid*3]; ky[tid]=kern[tid*3+1]; kz[tid]=kern[tid*3+2]; }
    for (int i = tid; i < 4*29; i += 64) ((float*)lpool)[i] = 0.f;

    const int zA = max(cz0 - 1, 0);
    const int zB = min(cz0 + len, GRIDC - 1);

    // chunk table (wave-uniform)
    int cB[9], cS[9], cL[9];
    int ncand = 0;
#pragma unroll
    for (int a = 0; a < 3; ++a)
#pragma unroll
        for (int b = 0; b < 3; ++b) {
            int c = a * 3 + b;
            int xx = cx - 1 + a, yy = cy - 1 + b;
            bool v = ((unsigned)xx < GRIDC) && ((unsigned)yy < GRIDC);
            int cc = v ? (xx * GRIDC + yy) * GRIDC : 0;
            int s0 = v ? cstart[cc + zA] : 0;
            int e0 = v ? cstart[cc + zB + 1] : 0;
            cS[c] = s0; cB[c] = ncand; cL[c] = e0 - s0;
            ncand += e0 - s0;
        }
    const bool slabOvf = (ncand > SLAB_CAP);
    const int nscan = min(ncand, SLAB_CAP);

    // stage slab (coalesced); .w = |s|^2
#pragma unroll
    for (int c = 0; c < 9; ++c) {
        int lim = min(cL[c], max(0, SLAB_CAP - cB[c]));
        for (int i = tid; i < lim; i += 64) {
            float4 p = sorted[cS[c] + i];
            p.w = p.x*p.x + p.y*p.y + p.z*p.z;
            cand[cB[c] + i] = p;
        }
    }
    __syncthreads();

    const int gz0 = cz0 >> 1;
    const int lb = tid * LIST_STRIDE;

    for (int qbase = 0; qbase < qn; qbase += 64) {
        const bool active = (qbase + tid) < qn;
        const int qidx = qb + qbase + (active ? tid : 0);

        if (slabOvf) {        // degenerate: push everything to phase B
            if (active) {
                int pos = atomicAdd(ucnt, 1);
                if (pos < UNRES_CAP) ulst[pos] = qidx;
            }
            continue;
        }

        const int qoff = cB[4] + (qidx - cS[4]);   // center column staged
        const float4 Q = cand[qoff];
        const float qq = Q.w;
        const float m2x = -2.f*Q.x, m2y = -2.f*Q.y, m2z = -2.f*Q.z;

        // ---- collect: whole slab, uniform bounds, packed u32 list
        int cnt = 0;
#pragma unroll 4
        for (int j = 0; j < nscan; ++j) {
            float4 s = cand[j];
            float d = fmaf(m2x, s.x, s.w);
            d = fmaf(m2y, s.y, d);
            d = fmaf(m2z, s.z, d);
            d += qq;
            d = fmaxf(d, 0.f);                     // self-point: exact 0
            if (d < R0SQ) {
                if (cnt < LIST_CAP)
                    lst[lb + cnt] = (__float_as_uint(d) & ~1023u) | (unsigned)j;
                ++cnt;
            }
        }

        const bool resolved = active && (cnt >= KNN) && (cnt <= LIST_CAP);
        if (active && !resolved) {
            int pos = atomicAdd(ucnt, 1);
            if (pos < UNRES_CAP) ulst[pos] = qidx;
        }

        if (resolved) {
            // ---- select: branchless u32 top-10 over ~25-entry list
            unsigned kd[KNN];
#pragma unroll
            for (int u = 0; u < KNN; ++u) kd[u] = 0xFFFFFFFFu;
            for (int i = 0; i < cnt; ++i) ins10(kd, lst[lb + i]);

            // ---- influence
            float acc[PK];
#pragma unroll
            for (int p = 0; p < PK; ++p) acc[p] = 0.f;
#pragma unroll
            for (int u = 0; u < KNN; ++u) {
                float4 nb = cand[kd[u] & 1023u];
                float rx = nb.x - Q.x, ry = nb.y - Q.y, rz = nb.z - Q.z;
#pragma unroll
                for (int p = 0; p < PK; ++p) {
                    float dx = rx - kx[p], dy = ry - ky[p], dz = rz - kz[p];
                    float d2 = dx * dx;
                    d2 = fmaf(dy, dy, d2);
                    d2 = fmaf(dz, dz, d2);
                    acc[p] += fmaxf(0.f, fmaf(-INVSIG, sqrtf(d2), 1.f));
                }
            }

            // ---- pooling: LDS aggregate (fast path) or direct global (rare)
            int gx = min(max((int)floorf(Q.x / 0.1f), 0), GRIDB - 1);
            int gy = min(max((int)floorf(Q.y / 0.1f), 0), GRIDB - 1);
            int gz = min(max((int)floorf(Q.z / 0.1f), 0), GRIDB - 1);
            int row = gz - gz0;
            if (gx == (cx >> 1) && gy == (cy >> 1) && (unsigned)row < 4u) {
                atomicAdd(&lpool[row][0], 1.0f);
                atomicAdd(&lpool[row][1], Q.x);
                atomicAdd(&lpool[row][2], Q.y);
                atomicAdd(&lpool[row][3], Q.z);
#pragma unroll
                for (int p = 0; p < PK; ++p) atomicAdd(&lpool[row][4 + p], acc[p]);
            } else {
                int sg = (gx * GRIDB + gy) * GRIDB + gz;
                atomicAdd(&pool[sg], 1.0f);
                atomicAdd(&pool[NSEG + sg*3+0], Q.x);
                atomicAdd(&pool[NSEG + sg*3+1], Q.y);
                atomicAdd(&pool[NSEG + sg*3+2], Q.z);
#pragma unroll
                for (int p = 0; p < PK; ++p) atomicAdd(&pool[NSEG*4 + sg*PK + p], acc[p]);
            }
        }
    }

    __syncthreads();
    // flush LDS pool (one global atomic per nonzero component)
    const int segb = ((cx >> 1) * GRIDB + (cy >> 1)) * GRIDB + gz0;
    for (int i = tid; i < 4*29; i += 64) {
        int row = i / 29, comp = i - row * 29;
        float v = lpool[row][comp];
        if (v != 0.f) {
            int sg = segb + row;
            if (comp == 0)      atomicAdd(&pool[sg], v);
            else if (comp < 4)  atomicAdd(&pool[NSEG + sg*3 + comp-1], v);
            else                atomicAdd(&pool[NSEG*4 + sg*PK + comp-4], v);
        }
    }
}

// ---- Phase B: one wave per unresolved query; cooperative exact window scan ----
__global__ __launch_bounds__(64) void phaseB(
    const float4* __restrict__ sorted,
    const int*    __restrict__ cstart,
    const float*  __restrict__ kern,
    float*        __restrict__ pool,
    const int*    __restrict__ ucnt,
    const int*    __restrict__ ulst)
{
    __shared__ float accL[KNN][PK];
    const int lane = threadIdx.x;
    const int n = min(*ucnt, UNRES_CAP);

    for (int w = blockIdx.x; w < n; w += gridDim.x) {
        const int qidx = ulst[w];
        const float4 Q = sorted[qidx];
        const int cqx = min((int)(Q.x * (float)GRIDC), GRIDC - 1);
        const int cqy = min((int)(Q.y * (float)GRIDC), GRIDC - 1);
        const int cqz = min((int)(Q.z * (float)GRIDC), GRIDC - 1);

        unsigned long long res[KNN];
        int r = 2;
        while (true) {
            unsigned long long kd[KNN];
#pragma unroll
            for (int u = 0; u < KNN; ++u) kd[u] = ~0ull;
            const int x0 = max(cqx-r,0), x1 = min(cqx+r,GRIDC-1);
            const int y0 = max(cqy-r,0), y1 = min(cqy+r,GRIDC-1);
            const int z0 = max(cqz-r,0), z1 = min(cqz+r,GRIDC-1);
            for (int xx = x0; xx <= x1; ++xx)
                for (int yy = y0; yy <= y1; ++yy) {
                    const int cc = (xx * GRIDC + yy) * GRIDC;
                    const int b0 = cstart[cc + z0], e0 = cstart[cc + z1 + 1];
                    for (int i = b0 + lane; i < e0; i += 64) {   // coalesced
                        float4 s = sorted[i];
                        float dx = Q.x - s.x, dy = Q.y - s.y, dz = Q.z - s.z;
                        float d = dx * dx;
                        d = fmaf(dy, dy, d);
                        d = fmaf(dz, dz, d);
                        d = fmaxf(d, 0.f);
                        unsigned long long pk =
                            ((unsigned long long)__float_as_uint(d) << 32) | (unsigned)i;
                        if (pk < kd[KNN-1]) ins10_64(kd, pk);
                    }
                }
            // wave-wide top-10 by 10 min-extraction rounds
            int cur = 0;
#pragma unroll
            for (int t = 0; t < KNN; ++t) {
                unsigned long long mine = (cur < KNN) ? kd[cur] : ~0ull;
                unsigned long long m = mine;
#pragma unroll
                for (int off = 1; off < 64; off <<= 1) {
                    unsigned long long o = __shfl_xor(m, off);
                    m = (o < m) ? o : m;
                }
                res[t] = m;
                if (mine == m && m != ~0ull) ++cur;
            }
            float d10 = __uint_as_float((unsigned)(res[KNN-1] >> 32));
            float rr = r * CELLK;
            if (d10 <= rr * rr || r >= GRIDC) break;   // NaN-safe
            ++r;
        }

        // influence: lanes 0..9 each take one neighbor
        if (lane < KNN) {
            float acc[PK];
#pragma unroll
            for (int p = 0; p < PK; ++p) acc[p] = 0.f;
            if (res[lane] != ~0ull) {
                float4 nb = sorted[(unsigned)(res[lane] & 0xFFFFFFFFull)];
                float rx = nb.x - Q.x, ry = nb.y - Q.y, rz = nb.z - Q.z;
#pragma unroll
                for (int p = 0; p < PK; ++p) {
                    float dx = rx - kern[p*3], dy = ry - kern[p*3+1], dz = rz - kern[p*3+2];
                    float d2 = dx * dx;
                    d2 = fmaf(dy, dy, d2);
                    d2 = fmaf(dz, dz, d2);
                    acc[p] += fmaxf(0.f, fmaf(-INVSIG, sqrtf(d2), 1.f));
                }
            }
#pragma unroll
            for (int p = 0; p < PK; ++p) accL[lane][p] = acc[p];
        }
        __syncthreads();

        int gx = min(max((int)floorf(Q.x / 0.1f), 0), GRIDB - 1);
        int gy = min(max((int)floorf(Q.y / 0.1f), 0), GRIDB - 1);
        int gz = min(max((int)floorf(Q.z / 0.1f), 0), GRIDB - 1);
        int sg = (gx * GRIDB + gy) * GRIDB + gz;
        if (lane < PK) {
            float v = 0.f;
#pragma unroll
            for (int u = 0; u < KNN; ++u) v += accL[u][lane];
            atomicAdd(&pool[NSEG*4 + sg*PK + lane], v);
        } else if (lane == 32) atomicAdd(&pool[sg], 1.0f);
        else if (lane == 33) atomicAdd(&pool[NSEG + sg*3+0], Q.x);
        else if (lane == 34) atomicAdd(&pool[NSEG + sg*3+1], Q.y);
        else if (lane == 35) atomicAdd(&pool[NSEG + sg*3+2], Q.z);
        __syncthreads();
    }
}

__global__ __launch_bounds__(64) void finalize(
    const float* __restrict__ pool,
    const float* __restrict__ W,
    float* __restrict__ out)
{
    const int s = blockIdx.x;
    const int d = threadIdx.x;
    __shared__ float sInfl[PK];
    if (d < PK) sInfl[d] = pool[NSEG*4 + s*PK + d];
    __syncthreads();

    float c = fmaxf(pool[s], 1.0f);
    float inv = 1.0f / c;

    float a = 0.f;
#pragma unroll
    for (int p = 0; p < PK; ++p) a = fmaf(sInfl[p], W[p*NCOUT + d], a);
    out[NSEG*3 + s*NCOUT + d] = a * inv;

    if (d < 3) out[s*3 + d] = pool[NSEG + s*3 + d] * inv;
}

extern "C" void kernel_launch(void* const* d_in, const int* in_sizes, int n_in,
                              void* d_out, int out_size, void* d_ws, size_t ws_size,
                              hipStream_t stream)
{
    const float* pts  = (const float*)d_in[0];
    const float* kern = (const float*)d_in[1];
    const float* W    = (const float*)d_in[2];
    float* out = (float*)d_out;
    char*  ws  = (char*)d_ws;

    float4* sorted = (float4*)(ws + OFF_SORTED);
    int*    hist   = (int*)   (ws + OFF_HIST);
    int*    cstart = (int*)   (ws + OFF_CSTART);
    int*    cursor = (int*)   (ws + OFF_CURSOR);
    float*  pool   = (float*) (ws + OFF_POOL);
    int*    ucnt   = (int*)   (ws + OFF_UCNT);
    int*    ulst   = (int*)   (ws + OFF_ULST);

    hipMemsetAsync(hist, 0, MEMSET_SIZE, stream);

    hist_kernel   <<<NPTS/256, 256, 0, stream>>>(pts, hist);
    scan_kernel   <<<1,        256, 0, stream>>>(hist, cstart, cursor);
    scatter_kernel<<<NPTS/256, 256, 0, stream>>>(pts, cursor, sorted);
    phaseA        <<<400*3,     64, 0, stream>>>(sorted, cstart, kern, pool, ucnt, ulst);
    phaseB        <<<4096,      64, 0, stream>>>(sorted, cstart, kern, pool, ucnt, ulst);
    finalize      <<<NSEG,      64, 0, stream>>>(pool, W, out);
}